// Round 5
// baseline (748.817 us; speedup 1.0000x reference)
//
#include <hip/hip_runtime.h>
#include <hip/hip_bf16.h>
#include <math.h>

// ---------------------------------------------------------------------------
// Transformer block, MI355X/gfx950. bf16 MFMA compute, fp32 accumulate.
// x:[4,2048,1024] f32. M = 8192 tokens, DIM=1024, HEADS=16, DHEAD=64, MLP=4096.
// ---------------------------------------------------------------------------

typedef __bf16 bf16;
typedef __bf16 bf16x8 __attribute__((ext_vector_type(8)));
typedef __bf16 bf16x4 __attribute__((ext_vector_type(4)));
typedef float  f32x4  __attribute__((ext_vector_type(4)));
typedef unsigned int u32;

#define MFMA_16x16x32(a, b, c) __builtin_amdgcn_mfma_f32_16x16x32_bf16((a), (b), (c), 0, 0, 0)

__device__ __forceinline__ void gl_lds16(const void* g, void* l) {
    __builtin_amdgcn_global_load_lds(
        (const __attribute__((address_space(1))) u32*)g,
        (__attribute__((address_space(3))) u32*)l, 16, 0, 0);
}

// fast exact-enough GELU: tanh form, e = exp2(2u*log2e), g = x*e/(e+1)
__device__ __forceinline__ float fast_gelu(float x) {
    const float u = x * (0.7978845608028654f + 0.03567740814183f * x * x);
    const float e = __builtin_amdgcn_exp2f(u * 2.8853900817779268f);
    return x * e * __builtin_amdgcn_rcpf(e + 1.0f);
}

// ---------------------------------------------------------------------------
// fp32 [R][C]  ->  bf16 [C][R]  (transposed weight for B-operand contiguity)
// ---------------------------------------------------------------------------
__global__ __launch_bounds__(256) void transpose_f32_bf16(
    const float* __restrict__ in, bf16* __restrict__ out, int R, int C)
{
    __shared__ float tile[32][33];
    const int cb = blockIdx.x * 32, rb = blockIdx.y * 32;
    const int c = threadIdx.x & 31, r0 = threadIdx.x >> 5;
#pragma unroll
    for (int i = 0; i < 4; ++i) {
        int r = r0 + i * 8;
        tile[r][c] = in[(size_t)(rb + r) * C + cb + c];
    }
    __syncthreads();
#pragma unroll
    for (int i = 0; i < 4; ++i) {
        int rr = r0 + i * 8;
        out[(size_t)(cb + rr) * R + rb + c] = (bf16)tile[c][rr];
    }
}

// ---------------------------------------------------------------------------
// V slice of qkv [8192][3072] -> VT [64 bh][64 d][2048 tok] bf16
// ---------------------------------------------------------------------------
__global__ __launch_bounds__(256) void transpose_v(
    const bf16* __restrict__ qkv, bf16* __restrict__ VT)
{
    __shared__ float tile[32][33];
    const int tokb = blockIdx.x * 32;
    const int db   = blockIdx.y * 32;
    const int bh   = blockIdx.z;
    const int b = bh >> 4, h = bh & 15;
    const int c = threadIdx.x & 31, r0 = threadIdx.x >> 5;
#pragma unroll
    for (int i = 0; i < 4; ++i) {
        int r = r0 + i * 8;
        tile[r][c] = (float)qkv[(size_t)(b * 2048 + tokb + r) * 3072 + 2048 + h * 64 + db + c];
    }
    __syncthreads();
#pragma unroll
    for (int i = 0; i < 4; ++i) {
        int rr = r0 + i * 8;
        VT[((size_t)bh * 64 + db + rr) * 2048 + tokb + c] = (bf16)tile[c][rr];
    }
}

// ---------------------------------------------------------------------------
// LayerNorm: one wave per token, f32 in -> bf16 out. grid 2048, block 256
// ---------------------------------------------------------------------------
__global__ __launch_bounds__(256) void ln_kernel(
    const float* __restrict__ x, const float* __restrict__ g,
    const float* __restrict__ b, bf16* __restrict__ out)
{
    const int lane = threadIdx.x & 63;
    const int wv   = threadIdx.x >> 6;
    const size_t token = (size_t)blockIdx.x * 4 + wv;
    const float* xr = x + token * 1024;
    float4 v[4];
    float s = 0.f, ss = 0.f;
#pragma unroll
    for (int c = 0; c < 4; ++c) {
        v[c] = *(const float4*)(xr + c * 256 + lane * 4);
        s  += v[c].x + v[c].y + v[c].z + v[c].w;
        ss += v[c].x * v[c].x + v[c].y * v[c].y + v[c].z * v[c].z + v[c].w * v[c].w;
    }
#pragma unroll
    for (int off = 32; off > 0; off >>= 1) {
        s  += __shfl_xor(s, off);
        ss += __shfl_xor(ss, off);
    }
    const float mu  = s * (1.0f / 1024.0f);
    const float var = ss * (1.0f / 1024.0f) - mu * mu;
    const float rs  = rsqrtf(var + 1e-5f);
    bf16* orow = out + token * 1024;
#pragma unroll
    for (int c = 0; c < 4; ++c) {
        float4 gg = *(const float4*)(g + c * 256 + lane * 4);
        float4 bb = *(const float4*)(b + c * 256 + lane * 4);
        bf16x4 o;
        o[0] = (bf16)((v[c].x - mu) * rs * gg.x + bb.x);
        o[1] = (bf16)((v[c].y - mu) * rs * gg.y + bb.y);
        o[2] = (bf16)((v[c].z - mu) * rs * gg.z + bb.z);
        o[3] = (bf16)((v[c].w - mu) * rs * gg.w + bb.w);
        *(bf16x4*)(orow + c * 256 + lane * 4) = o;
    }
}

// ---------------------------------------------------------------------------
// GEMM: A[M,K] bf16 x Bt[N,K] bf16 -> out [M,N]. 128x128 tile, BK=64,
// DOUBLE-BUFFERED: stage k+1 before computing k, single barrier/iter ->
// the vmcnt(0) drain lands after the MFMAs, overlapping transfer w/ compute.
// Operand-swapped MFMA: lane holds 4 consecutive cols of one row.
// EPI: 0 = bf16; 1 = +bias +resid(f32) -> f32; 2 = +bias, fast GELU -> bf16
// ---------------------------------------------------------------------------
template <int EPI>
__global__ __launch_bounds__(256) void gemm_bt(
    const bf16* __restrict__ A, const bf16* __restrict__ Bt,
    const float* __restrict__ bias, const float* __restrict__ resid,
    void* __restrict__ outp, int M, int N, int K)
{
    __shared__ __align__(16) bf16 sA[2][8][128][8];   // 32 KB
    __shared__ __align__(16) bf16 sB[2][8][128][8];   // 32 KB

    const int tid  = threadIdx.x;
    const int lane = tid & 63;
    const int wv   = tid >> 6;
    const int quad = lane >> 4;
    const int l16  = lane & 15;
    const int M0 = blockIdx.x * 128;
    const int N0 = blockIdx.y * 128;
    const int wm = (wv >> 1) * 64;
    const int wn = (wv & 1) * 64;

    f32x4 acc[4][4] = {};

    const bf16* Ab = A  + (size_t)M0 * K;
    const bf16* Bb = Bt + (size_t)N0 * K;

    // stage BK=64 tile pair into buffer `buf`
#define STAGE(k0, buf)                                                        \
    {                                                                         \
        _Pragma("unroll")                                                     \
        for (int c = 0; c < 4; ++c) {                                         \
            const int f = c * 256 + tid;                                      \
            const int qa = f >> 7, ra = f & 127;                              \
            gl_lds16(Ab + (size_t)ra * K + (k0) + qa * 8, &sA[buf][qa][ra][0]);\
            gl_lds16(Bb + (size_t)ra * K + (k0) + qa * 8, &sB[buf][qa][ra][0]);\
        }                                                                     \
    }

    STAGE(0, 0);
    __syncthreads();

    const int nk = K >> 6;
    for (int kk = 0; kk < nk; ++kk) {
        const int cur = kk & 1;
        if (kk + 1 < nk) STAGE((kk + 1) << 6, cur ^ 1);

#pragma unroll
        for (int s = 0; s < 2; ++s) {
            bf16x8 af[4], bfr[4];
#pragma unroll
            for (int t = 0; t < 4; ++t)
                af[t] = *(const bf16x8*)&sA[cur][s * 4 + quad][wm + t * 16 + l16][0];
#pragma unroll
            for (int t = 0; t < 4; ++t)
                bfr[t] = *(const bf16x8*)&sB[cur][s * 4 + quad][wn + t * 16 + l16][0];
#pragma unroll
            for (int tm = 0; tm < 4; ++tm)
#pragma unroll
                for (int tn = 0; tn < 4; ++tn)
                    acc[tm][tn] = MFMA_16x16x32(bfr[tn], af[tm], acc[tm][tn]);
        }
        __syncthreads();
    }
#undef STAGE

    // swapped C layout: lane l16 = output row, regs r = 4 consecutive cols
#pragma unroll
    for (int tm = 0; tm < 4; ++tm) {
        const int row = M0 + wm + tm * 16 + l16;
#pragma unroll
        for (int tn = 0; tn < 4; ++tn) {
            const int col = N0 + wn + tn * 16 + quad * 4;
            const size_t idx = (size_t)row * N + col;
            const f32x4 v = acc[tm][tn];
            if (EPI == 0) {
                bf16x4 o;
#pragma unroll
                for (int r = 0; r < 4; ++r) o[r] = (bf16)v[r];
                *(bf16x4*)((bf16*)outp + idx) = o;
            } else if (EPI == 1) {
                const f32x4 b4 = *(const f32x4*)(bias + col);
                const f32x4 r4 = *(const f32x4*)(resid + idx);
                *(f32x4*)((float*)outp + idx) = v + b4 + r4;
            } else {
                const f32x4 b4 = *(const f32x4*)(bias + col);
                bf16x4 o;
#pragma unroll
                for (int r = 0; r < 4; ++r) o[r] = (bf16)fast_gelu(v[r] + b4[r]);
                *(bf16x4*)((bf16*)outp + idx) = o;
            }
        }
    }
}

// ---------------------------------------------------------------------------
// Flash attention, no-max softmax (scores ~N(0,1): exp2 args |.|<~10, safe).
// Double-buffered K/V staging, single barrier per k-tile.
// qkv: [8192][3072] bf16; VT: [64 bh][64 d][2048] bf16.
// grid (16 q-tiles, 64 bh), block 256. Wave = 32 q rows; k-tile = 64 keys.
// ---------------------------------------------------------------------------
__global__ __launch_bounds__(256, 4) void attn_kernel(
    const bf16* __restrict__ qkv, const bf16* __restrict__ VT,
    bf16* __restrict__ attn_out)
{
    __shared__ __align__(16) bf16 sK[2][4096];
    __shared__ __align__(16) bf16 sV[2][4096];
    __shared__ __align__(16) bf16 sP[4][32][72];

    const int bh = blockIdx.y, b = bh >> 4, h = bh & 15;
    const int tid = threadIdx.x, lane = tid & 63, wv = tid >> 6;
    const int quad = lane >> 4, l16 = lane & 15;
    const size_t tok0 = (size_t)b * 2048;
    const int q0 = blockIdx.x * 128 + wv * 32;

    bf16x8 qf[2][2];
#pragma unroll
    for (int mi = 0; mi < 2; ++mi)
#pragma unroll
        for (int c = 0; c < 2; ++c) {
            bf16x8 t = *(const bf16x8*)(qkv + (tok0 + q0 + mi * 16 + l16) * 3072 + h * 64 + c * 32 + quad * 8);
#pragma unroll
            for (int j = 0; j < 8; ++j) t[j] = (bf16)((float)t[j] * 0.18033688011112042f);
            qf[mi][c] = t;
        }

    f32x4 o[2][4] = {};
    float l[2][4] = {};

    const int fA = tid, fB = tid + 256;
    const int cKA = fA >> 8, keyA = (fA >> 2) & 63, qcA = fA & 3;
    const int cKB = fB >> 8, keyB = (fB >> 2) & 63, qcB = fB & 3;
    const int dVA = fA >> 3, ccA = fA & 7;
    const int dVB = fB >> 3, ccB = fB & 7;
    const bf16* Kb = qkv + 1024 + h * 64;
    const bf16* Vb = VT + (size_t)bh * 64 * 2048;

#define STAGE_KV(kb, buf)                                                                          \
    {                                                                                              \
        gl_lds16(Kb + (tok0 + (kb) + keyA) * 3072 + cKA * 32 + ((qcA ^ (keyA & 3)) * 8),           \
                 sK[buf] + fA * 8);                                                                \
        gl_lds16(Kb + (tok0 + (kb) + keyB) * 3072 + cKB * 32 + ((qcB ^ (keyB & 3)) * 8),           \
                 sK[buf] + fB * 8);                                                                \
        gl_lds16(Vb + (size_t)dVA * 2048 + (kb) + ((ccA ^ (dVA & 7)) * 8), sV[buf] + fA * 8);      \
        gl_lds16(Vb + (size_t)dVB * 2048 + (kb) + ((ccB ^ (dVB & 7)) * 8), sV[buf] + fB * 8);      \
    }

    STAGE_KV(0, 0);
    __syncthreads();

    for (int kt = 0; kt < 32; ++kt) {
        const int cur = kt & 1;
        if (kt + 1 < 32) STAGE_KV((kt + 1) * 64, cur ^ 1);

        f32x4 s[2][4];
#pragma unroll
        for (int ct = 0; ct < 4; ++ct) {
            const int key = ct * 16 + l16;
            const int ch = quad ^ (l16 & 3);
            bf16x8 k0 = *(const bf16x8*)(sK[cur] + (key * 4 + ch) * 8);
            bf16x8 k1 = *(const bf16x8*)(sK[cur] + (256 + key * 4 + ch) * 8);
#pragma unroll
            for (int mi = 0; mi < 2; ++mi) {
                f32x4 z = {};
                z = MFMA_16x16x32(qf[mi][0], k0, z);
                z = MFMA_16x16x32(qf[mi][1], k1, z);
                s[mi][ct] = z;
            }
        }
#pragma unroll
        for (int mi = 0; mi < 2; ++mi)
#pragma unroll
            for (int ct = 0; ct < 4; ++ct)
#pragma unroll
                for (int r = 0; r < 4; ++r) {
                    const float p = __builtin_amdgcn_exp2f(s[mi][ct][r]);
                    l[mi][r] += p;
                    sP[wv][mi * 16 + quad * 4 + r][ct * 16 + l16] = (bf16)p;
                }
        bf16x8 vb[4][2];
#pragma unroll
        for (int dt = 0; dt < 4; ++dt) {
            const int d = dt * 16 + l16;
            vb[dt][0] = *(const bf16x8*)(sV[cur] + (d * 8 + (quad ^ (l16 & 7))) * 8);
            vb[dt][1] = *(const bf16x8*)(sV[cur] + (d * 8 + ((quad + 4) ^ (l16 & 7))) * 8);
        }
#pragma unroll
        for (int mi = 0; mi < 2; ++mi) {
            bf16x8 p0 = *(const bf16x8*)&sP[wv][mi * 16 + l16][quad * 8];
            bf16x8 p1 = *(const bf16x8*)&sP[wv][mi * 16 + l16][32 + quad * 8];
#pragma unroll
            for (int dt = 0; dt < 4; ++dt) {
                o[mi][dt] = MFMA_16x16x32(p0, vb[dt][0], o[mi][dt]);
                o[mi][dt] = MFMA_16x16x32(p1, vb[dt][1], o[mi][dt]);
            }
        }
        __syncthreads();
    }
#undef STAGE_KV

#pragma unroll
    for (int mi = 0; mi < 2; ++mi) {
        float rl[4];
#pragma unroll
        for (int r = 0; r < 4; ++r) {
            float t = l[mi][r];
            t += __shfl_xor(t, 1); t += __shfl_xor(t, 2);
            t += __shfl_xor(t, 4); t += __shfl_xor(t, 8);
            rl[r] = 1.0f / t;
        }
#pragma unroll
        for (int dt = 0; dt < 4; ++dt)
#pragma unroll
            for (int r = 0; r < 4; ++r) {
                const size_t tok = tok0 + q0 + mi * 16 + quad * 4 + r;
                attn_out[tok * 1024 + h * 64 + dt * 16 + l16] = (bf16)(o[mi][dt][r] * rl[r]);
            }
    }
}

// ---------------------------------------------------------------------------
extern "C" void kernel_launch(void* const* d_in, const int* in_sizes, int n_in,
                              void* d_out, int out_size, void* d_ws, size_t ws_size,
                              hipStream_t stream)
{
    const float* x     = (const float*)d_in[0];
    const float* ln1_g = (const float*)d_in[1];
    const float* ln1_b = (const float*)d_in[2];
    const float* w_qkv = (const float*)d_in[3];
    const float* w_out = (const float*)d_in[4];
    const float* b_out = (const float*)d_in[5];
    const float* ln2_g = (const float*)d_in[6];
    const float* ln2_b = (const float*)d_in[7];
    const float* w1    = (const float*)d_in[8];
    const float* b1    = (const float*)d_in[9];
    const float* w2    = (const float*)d_in[10];
    const float* b2    = (const float*)d_in[11];
    float* out = (float*)d_out;

    char* ws = (char*)d_ws;
    bf16*  h      = (bf16*)(ws);                    // 16 MB
    bf16*  big    = (bf16*)(ws + 16777216);         // 64 MB (qkv, then mlp1)
    bf16*  attn_o = (bf16*)(ws + 83886080);         // 16 MB
    float* x_mid  = (float*)(ws + 100663296);       // 32 MB
    bf16*  VT     = (bf16*)(ws + 100663296);        // 16 MB (dead before x_mid)
    bf16*  wT_qkv = (bf16*)(ws + 134217728);
    bf16*  wT_out = (bf16*)(ws + 140509184);
    bf16*  wT_1   = (bf16*)(ws + 142606336);
    bf16*  wT_2   = (bf16*)(ws + 150994944);

    transpose_f32_bf16<<<dim3(3072/32, 1024/32), 256, 0, stream>>>(w_qkv, wT_qkv, 1024, 3072);
    transpose_f32_bf16<<<dim3(1024/32, 1024/32), 256, 0, stream>>>(w_out, wT_out, 1024, 1024);
    transpose_f32_bf16<<<dim3(4096/32, 1024/32), 256, 0, stream>>>(w1,    wT_1,   1024, 4096);
    transpose_f32_bf16<<<dim3(1024/32, 4096/32), 256, 0, stream>>>(w2,    wT_2,   4096, 1024);

    ln_kernel<<<2048, 256, 0, stream>>>(x, ln1_g, ln1_b, h);

    gemm_bt<0><<<dim3(64, 24), 256, 0, stream>>>(h, wT_qkv, nullptr, nullptr, big, 8192, 3072, 1024);

    transpose_v<<<dim3(64, 2, 64), 256, 0, stream>>>(big, VT);

    attn_kernel<<<dim3(16, 64), 256, 0, stream>>>(big, VT, attn_o);

    gemm_bt<1><<<dim3(64, 8), 256, 0, stream>>>(attn_o, wT_out, b_out, x, x_mid, 8192, 1024, 1024);

    ln_kernel<<<2048, 256, 0, stream>>>(x_mid, ln2_g, ln2_b, h);

    gemm_bt<2><<<dim3(64, 32), 256, 0, stream>>>(h, wT_1, b1, nullptr, big, 8192, 4096, 1024);

    gemm_bt<1><<<dim3(64, 8), 256, 0, stream>>>(big, wT_2, b2, x_mid, out, 8192, 1024, 4096);
}

// Round 6
// 684.585 us; speedup vs baseline: 1.0938x; 1.0938x over previous
//
#include <hip/hip_runtime.h>
#include <hip/hip_bf16.h>
#include <math.h>

// ---------------------------------------------------------------------------
// Transformer block, MI355X/gfx950. bf16 MFMA compute, fp32 accumulate.
// x:[4,2048,1024] f32. M = 8192 tokens, DIM=1024, HEADS=16, DHEAD=64, MLP=4096.
// ---------------------------------------------------------------------------

typedef __bf16 bf16;
typedef __bf16 bf16x8 __attribute__((ext_vector_type(8)));
typedef __bf16 bf16x4 __attribute__((ext_vector_type(4)));
typedef float  f32x4  __attribute__((ext_vector_type(4)));
typedef unsigned int u32;

#define MFMA_16x16x32(a, b, c) __builtin_amdgcn_mfma_f32_16x16x32_bf16((a), (b), (c), 0, 0, 0)

__device__ __forceinline__ void gl_lds16(const void* g, void* l) {
    __builtin_amdgcn_global_load_lds(
        (const __attribute__((address_space(1))) u32*)g,
        (__attribute__((address_space(3))) u32*)l, 16, 0, 0);
}

// fast exact-enough GELU: tanh form, e = exp2(2u*log2e), g = x*e/(e+1)
__device__ __forceinline__ float fast_gelu(float x) {
    const float u = x * (0.7978845608028654f + 0.03567740814183f * x * x);
    const float e = __builtin_amdgcn_exp2f(u * 2.8853900817779268f);
    return x * e * __builtin_amdgcn_rcpf(e + 1.0f);
}

// ---------------------------------------------------------------------------
// fp32 [R][C]  ->  bf16 [C][R]  (transposed weight for B-operand contiguity)
// ---------------------------------------------------------------------------
__global__ __launch_bounds__(256) void transpose_f32_bf16(
    const float* __restrict__ in, bf16* __restrict__ out, int R, int C)
{
    __shared__ float tile[32][33];
    const int cb = blockIdx.x * 32, rb = blockIdx.y * 32;
    const int c = threadIdx.x & 31, r0 = threadIdx.x >> 5;
#pragma unroll
    for (int i = 0; i < 4; ++i) {
        int r = r0 + i * 8;
        tile[r][c] = in[(size_t)(rb + r) * C + cb + c];
    }
    __syncthreads();
#pragma unroll
    for (int i = 0; i < 4; ++i) {
        int rr = r0 + i * 8;
        out[(size_t)(cb + rr) * R + rb + c] = (bf16)tile[c][rr];
    }
}

// ---------------------------------------------------------------------------
// V slice of qkv [8192][3072] -> VT [64 bh][64 d][2048 tok] bf16
// ---------------------------------------------------------------------------
__global__ __launch_bounds__(256) void transpose_v(
    const bf16* __restrict__ qkv, bf16* __restrict__ VT)
{
    __shared__ float tile[32][33];
    const int tokb = blockIdx.x * 32;
    const int db   = blockIdx.y * 32;
    const int bh   = blockIdx.z;
    const int b = bh >> 4, h = bh & 15;
    const int c = threadIdx.x & 31, r0 = threadIdx.x >> 5;
#pragma unroll
    for (int i = 0; i < 4; ++i) {
        int r = r0 + i * 8;
        tile[r][c] = (float)qkv[(size_t)(b * 2048 + tokb + r) * 3072 + 2048 + h * 64 + db + c];
    }
    __syncthreads();
#pragma unroll
    for (int i = 0; i < 4; ++i) {
        int rr = r0 + i * 8;
        VT[((size_t)bh * 64 + db + rr) * 2048 + tokb + c] = (bf16)tile[c][rr];
    }
}

// ---------------------------------------------------------------------------
// LayerNorm: one wave per token, f32 in -> bf16 out. grid 2048, block 256
// ---------------------------------------------------------------------------
__global__ __launch_bounds__(256) void ln_kernel(
    const float* __restrict__ x, const float* __restrict__ g,
    const float* __restrict__ b, bf16* __restrict__ out)
{
    const int lane = threadIdx.x & 63;
    const int wv   = threadIdx.x >> 6;
    const size_t token = (size_t)blockIdx.x * 4 + wv;
    const float* xr = x + token * 1024;
    float4 v[4];
    float s = 0.f, ss = 0.f;
#pragma unroll
    for (int c = 0; c < 4; ++c) {
        v[c] = *(const float4*)(xr + c * 256 + lane * 4);
        s  += v[c].x + v[c].y + v[c].z + v[c].w;
        ss += v[c].x * v[c].x + v[c].y * v[c].y + v[c].z * v[c].z + v[c].w * v[c].w;
    }
#pragma unroll
    for (int off = 32; off > 0; off >>= 1) {
        s  += __shfl_xor(s, off);
        ss += __shfl_xor(ss, off);
    }
    const float mu  = s * (1.0f / 1024.0f);
    const float var = ss * (1.0f / 1024.0f) - mu * mu;
    const float rs  = rsqrtf(var + 1e-5f);
    bf16* orow = out + token * 1024;
#pragma unroll
    for (int c = 0; c < 4; ++c) {
        float4 gg = *(const float4*)(g + c * 256 + lane * 4);
        float4 bb = *(const float4*)(b + c * 256 + lane * 4);
        bf16x4 o;
        o[0] = (bf16)((v[c].x - mu) * rs * gg.x + bb.x);
        o[1] = (bf16)((v[c].y - mu) * rs * gg.y + bb.y);
        o[2] = (bf16)((v[c].z - mu) * rs * gg.z + bb.z);
        o[3] = (bf16)((v[c].w - mu) * rs * gg.w + bb.w);
        *(bf16x4*)(orow + c * 256 + lane * 4) = o;
    }
}

// ---------------------------------------------------------------------------
// GEMM: A[M,K] bf16 x Bt[N,K] bf16 -> out [M,N]. 128x128 tile, BK=64,
// two-barrier K-loop (R4 structure — explicit dbuf regressed, see R5).
// 1D grid with XCD slab swizzle: xcd = id&7 owns an 8-block M-slab; N
// iterates innermost-every-8 so weight tiles get 8x back-to-back reuse and
// the 2MB A-slab stays L2-resident. Requires M == 8192 (Mb = 64).
// Operand-swapped MFMA: lane holds 4 consecutive cols of one row.
// EPI: 0 = bf16; 1 = +bias +resid(f32) -> f32; 2 = +bias, fast GELU -> bf16
// ---------------------------------------------------------------------------
template <int EPI>
__global__ __launch_bounds__(256, 4) void gemm_bt(
    const bf16* __restrict__ A, const bf16* __restrict__ Bt,
    const float* __restrict__ bias, const float* __restrict__ resid,
    void* __restrict__ outp, int M, int N, int K)
{
    __shared__ __align__(16) bf16 sA[8][128][8];   // 16 KB, quad = k/8 in BK=64
    __shared__ __align__(16) bf16 sB[8][128][8];   // 16 KB

    const int tid  = threadIdx.x;
    const int lane = tid & 63;
    const int wv   = tid >> 6;
    const int quad = lane >> 4;
    const int l16  = lane & 15;

    // XCD slab swizzle (HW heuristic: XCD = linear block id % 8)
    const int id  = blockIdx.x;
    const int xcd = id & 7, j = id >> 3;
    const int M0 = (xcd * 8 + (j & 7)) * 128;   // Mb = 64 fixed
    const int N0 = (j >> 3) * 128;

    const int wm = (wv >> 1) * 64;
    const int wn = (wv & 1) * 64;

    f32x4 acc[4][4] = {};

    for (int k0 = 0; k0 < K; k0 += 64) {
        __syncthreads();
#pragma unroll
        for (int c = 0; c < 4; ++c) {
            const int f = c * 256 + tid;
            const int qa = f >> 7, ra = f & 127;
            gl_lds16(A + (size_t)(M0 + ra) * K + k0 + qa * 8, &sA[qa][ra][0]);
        }
#pragma unroll
        for (int c = 0; c < 4; ++c) {
            const int f = c * 256 + tid;
            const int qa = f >> 7, ra = f & 127;
            gl_lds16(Bt + (size_t)(N0 + ra) * K + k0 + qa * 8, &sB[qa][ra][0]);
        }
        __syncthreads();

#pragma unroll
        for (int s = 0; s < 2; ++s) {
            bf16x8 af[4], bfr[4];
#pragma unroll
            for (int t = 0; t < 4; ++t)
                af[t] = *(const bf16x8*)&sA[s * 4 + quad][wm + t * 16 + l16][0];
#pragma unroll
            for (int t = 0; t < 4; ++t)
                bfr[t] = *(const bf16x8*)&sB[s * 4 + quad][wn + t * 16 + l16][0];
#pragma unroll
            for (int tm = 0; tm < 4; ++tm)
#pragma unroll
                for (int tn = 0; tn < 4; ++tn)
                    acc[tm][tn] = MFMA_16x16x32(bfr[tn], af[tm], acc[tm][tn]);
        }
    }

    // swapped C layout: lane l16 = output row, regs r = 4 consecutive cols
#pragma unroll
    for (int tm = 0; tm < 4; ++tm) {
        const int row = M0 + wm + tm * 16 + l16;
#pragma unroll
        for (int tn = 0; tn < 4; ++tn) {
            const int col = N0 + wn + tn * 16 + quad * 4;
            const size_t idx = (size_t)row * N + col;
            const f32x4 v = acc[tm][tn];
            if (EPI == 0) {
                bf16x4 o;
#pragma unroll
                for (int r = 0; r < 4; ++r) o[r] = (bf16)v[r];
                *(bf16x4*)((bf16*)outp + idx) = o;
            } else if (EPI == 1) {
                const f32x4 b4 = *(const f32x4*)(bias + col);
                const f32x4 r4 = *(const f32x4*)(resid + idx);
                *(f32x4*)((float*)outp + idx) = v + b4 + r4;
            } else {
                const f32x4 b4 = *(const f32x4*)(bias + col);
                bf16x4 o;
#pragma unroll
                for (int r = 0; r < 4; ++r) o[r] = (bf16)fast_gelu(v[r] + b4[r]);
                *(bf16x4*)((bf16*)outp + idx) = o;
            }
        }
    }
}

// ---------------------------------------------------------------------------
// Flash attention, no-max softmax (scores ~N(0,1): exp2 args |.|<~10, safe).
// qkv: [8192][3072] bf16; VT: [64 bh][64 d][2048] bf16.
// grid (16 q-tiles, 64 bh), block 256. Wave = 32 q rows; k-tile = 64 keys.
// (R4 structure — dbuf variant regressed, see R5.)
// ---------------------------------------------------------------------------
__global__ __launch_bounds__(256, 4) void attn_kernel(
    const bf16* __restrict__ qkv, const bf16* __restrict__ VT,
    bf16* __restrict__ attn_out)
{
    __shared__ __align__(16) bf16 sK[4096];
    __shared__ __align__(16) bf16 sV[4096];
    __shared__ __align__(16) bf16 sP[4][32][72];

    const int bh = blockIdx.y, b = bh >> 4, h = bh & 15;
    const int tid = threadIdx.x, lane = tid & 63, wv = tid >> 6;
    const int quad = lane >> 4, l16 = lane & 15;
    const size_t tok0 = (size_t)b * 2048;
    const int q0 = blockIdx.x * 128 + wv * 32;

    bf16x8 qf[2][2];
#pragma unroll
    for (int mi = 0; mi < 2; ++mi)
#pragma unroll
        for (int c = 0; c < 2; ++c) {
            bf16x8 t = *(const bf16x8*)(qkv + (tok0 + q0 + mi * 16 + l16) * 3072 + h * 64 + c * 32 + quad * 8);
#pragma unroll
            for (int j = 0; j < 8; ++j) t[j] = (bf16)((float)t[j] * 0.18033688011112042f);
            qf[mi][c] = t;
        }

    f32x4 o[2][4] = {};
    float l[2][4] = {};

    const int fA = tid, fB = tid + 256;
    const int cKA = fA >> 8, keyA = (fA >> 2) & 63, qcA = fA & 3;
    const int cKB = fB >> 8, keyB = (fB >> 2) & 63, qcB = fB & 3;
    const int dVA = fA >> 3, ccA = fA & 7;
    const int dVB = fB >> 3, ccB = fB & 7;
    const bf16* Kb = qkv + 1024 + h * 64;
    const bf16* Vb = VT + (size_t)bh * 64 * 2048;

    for (int kt = 0; kt < 32; ++kt) {
        const int kb = kt * 64;
        __syncthreads();
        gl_lds16(Kb + (tok0 + kb + keyA) * 3072 + cKA * 32 + ((qcA ^ (keyA & 3)) * 8), sK + fA * 8);
        gl_lds16(Kb + (tok0 + kb + keyB) * 3072 + cKB * 32 + ((qcB ^ (keyB & 3)) * 8), sK + fB * 8);
        gl_lds16(Vb + (size_t)dVA * 2048 + kb + ((ccA ^ (dVA & 7)) * 8), sV + fA * 8);
        gl_lds16(Vb + (size_t)dVB * 2048 + kb + ((ccB ^ (dVB & 7)) * 8), sV + fB * 8);
        __syncthreads();

        f32x4 s[2][4];
#pragma unroll
        for (int ct = 0; ct < 4; ++ct) {
            const int key = ct * 16 + l16;
            const int ch = quad ^ (l16 & 3);
            bf16x8 k0 = *(const bf16x8*)(sK + (key * 4 + ch) * 8);
            bf16x8 k1 = *(const bf16x8*)(sK + (256 + key * 4 + ch) * 8);
#pragma unroll
            for (int mi = 0; mi < 2; ++mi) {
                f32x4 z = {};
                z = MFMA_16x16x32(qf[mi][0], k0, z);
                z = MFMA_16x16x32(qf[mi][1], k1, z);
                s[mi][ct] = z;
            }
        }
#pragma unroll
        for (int mi = 0; mi < 2; ++mi)
#pragma unroll
            for (int ct = 0; ct < 4; ++ct)
#pragma unroll
                for (int r = 0; r < 4; ++r) {
                    const float p = __builtin_amdgcn_exp2f(s[mi][ct][r]);
                    l[mi][r] += p;
                    sP[wv][mi * 16 + quad * 4 + r][ct * 16 + l16] = (bf16)p;
                }
        bf16x8 vb[4][2];
#pragma unroll
        for (int dt = 0; dt < 4; ++dt) {
            const int d = dt * 16 + l16;
            vb[dt][0] = *(const bf16x8*)(sV + (d * 8 + (quad ^ (l16 & 7))) * 8);
            vb[dt][1] = *(const bf16x8*)(sV + (d * 8 + ((quad + 4) ^ (l16 & 7))) * 8);
        }
#pragma unroll
        for (int mi = 0; mi < 2; ++mi) {
            bf16x8 p0 = *(const bf16x8*)&sP[wv][mi * 16 + l16][quad * 8];
            bf16x8 p1 = *(const bf16x8*)&sP[wv][mi * 16 + l16][32 + quad * 8];
#pragma unroll
            for (int dt = 0; dt < 4; ++dt) {
                o[mi][dt] = MFMA_16x16x32(p0, vb[dt][0], o[mi][dt]);
                o[mi][dt] = MFMA_16x16x32(p1, vb[dt][1], o[mi][dt]);
            }
        }
    }

#pragma unroll
    for (int mi = 0; mi < 2; ++mi) {
        float rl[4];
#pragma unroll
        for (int r = 0; r < 4; ++r) {
            float t = l[mi][r];
            t += __shfl_xor(t, 1); t += __shfl_xor(t, 2);
            t += __shfl_xor(t, 4); t += __shfl_xor(t, 8);
            rl[r] = 1.0f / t;
        }
#pragma unroll
        for (int dt = 0; dt < 4; ++dt)
#pragma unroll
            for (int r = 0; r < 4; ++r) {
                const size_t tok = tok0 + q0 + mi * 16 + quad * 4 + r;
                attn_out[tok * 1024 + h * 64 + dt * 16 + l16] = (bf16)(o[mi][dt][r] * rl[r]);
            }
    }
}

// ---------------------------------------------------------------------------
extern "C" void kernel_launch(void* const* d_in, const int* in_sizes, int n_in,
                              void* d_out, int out_size, void* d_ws, size_t ws_size,
                              hipStream_t stream)
{
    const float* x     = (const float*)d_in[0];
    const float* ln1_g = (const float*)d_in[1];
    const float* ln1_b = (const float*)d_in[2];
    const float* w_qkv = (const float*)d_in[3];
    const float* w_out = (const float*)d_in[4];
    const float* b_out = (const float*)d_in[5];
    const float* ln2_g = (const float*)d_in[6];
    const float* ln2_b = (const float*)d_in[7];
    const float* w1    = (const float*)d_in[8];
    const float* b1    = (const float*)d_in[9];
    const float* w2    = (const float*)d_in[10];
    const float* b2    = (const float*)d_in[11];
    float* out = (float*)d_out;

    char* ws = (char*)d_ws;
    bf16*  h      = (bf16*)(ws);                    // 16 MB
    bf16*  big    = (bf16*)(ws + 16777216);         // 64 MB (qkv, then mlp1)
    bf16*  attn_o = (bf16*)(ws + 83886080);         // 16 MB
    float* x_mid  = (float*)(ws + 100663296);       // 32 MB
    bf16*  VT     = (bf16*)(ws + 100663296);        // 16 MB (dead before x_mid)
    bf16*  wT_qkv = (bf16*)(ws + 134217728);
    bf16*  wT_out = (bf16*)(ws + 140509184);
    bf16*  wT_1   = (bf16*)(ws + 142606336);
    bf16*  wT_2   = (bf16*)(ws + 150994944);

    transpose_f32_bf16<<<dim3(3072/32, 1024/32), 256, 0, stream>>>(w_qkv, wT_qkv, 1024, 3072);
    transpose_f32_bf16<<<dim3(1024/32, 1024/32), 256, 0, stream>>>(w_out, wT_out, 1024, 1024);
    transpose_f32_bf16<<<dim3(4096/32, 1024/32), 256, 0, stream>>>(w1,    wT_1,   1024, 4096);
    transpose_f32_bf16<<<dim3(1024/32, 4096/32), 256, 0, stream>>>(w2,    wT_2,   4096, 1024);

    ln_kernel<<<2048, 256, 0, stream>>>(x, ln1_g, ln1_b, h);

    // 1D grids: Mb=64 always; block count = 64 * (N/128)
    gemm_bt<0><<<64 * 24, 256, 0, stream>>>(h, wT_qkv, nullptr, nullptr, big, 8192, 3072, 1024);

    transpose_v<<<dim3(64, 2, 64), 256, 0, stream>>>(big, VT);

    attn_kernel<<<dim3(16, 64), 256, 0, stream>>>(big, VT, attn_o);

    gemm_bt<1><<<64 * 8, 256, 0, stream>>>(attn_o, wT_out, b_out, x, x_mid, 8192, 1024, 1024);

    ln_kernel<<<2048, 256, 0, stream>>>(x_mid, ln2_g, ln2_b, h);

    gemm_bt<2><<<64 * 32, 256, 0, stream>>>(h, wT_1, b1, nullptr, big, 8192, 4096, 1024);

    gemm_bt<1><<<64 * 8, 256, 0, stream>>>(big, wT_2, b2, x_mid, out, 8192, 1024, 4096);
}

// Round 7
// 520.920 us; speedup vs baseline: 1.4375x; 1.3142x over previous
//
#include <hip/hip_runtime.h>
#include <hip/hip_bf16.h>
#include <math.h>

// ---------------------------------------------------------------------------
// Transformer block, MI355X/gfx950. bf16 MFMA compute, fp32 accumulate.
// x:[4,2048,1024] f32. M = 8192 tokens, DIM=1024, HEADS=16, DHEAD=64, MLP=4096.
// ---------------------------------------------------------------------------

typedef __bf16 bf16;
typedef __bf16 bf16x8 __attribute__((ext_vector_type(8)));
typedef __bf16 bf16x4 __attribute__((ext_vector_type(4)));
typedef float  f32x4  __attribute__((ext_vector_type(4)));
typedef unsigned int u32;

#define MFMA_16x16x32(a, b, c) __builtin_amdgcn_mfma_f32_16x16x32_bf16((a), (b), (c), 0, 0, 0)

__device__ __forceinline__ void gl_lds16(const void* g, void* l) {
    __builtin_amdgcn_global_load_lds(
        (const __attribute__((address_space(1))) u32*)g,
        (__attribute__((address_space(3))) u32*)l, 16, 0, 0);
}

// fast exact-enough GELU: tanh form, e = exp2(2u*log2e), g = x*e/(e+1)
__device__ __forceinline__ float fast_gelu(float x) {
    const float u = x * (0.7978845608028654f + 0.03567740814183f * x * x);
    const float e = __builtin_amdgcn_exp2f(u * 2.8853900817779268f);
    return x * e * __builtin_amdgcn_rcpf(e + 1.0f);
}

// ---------------------------------------------------------------------------
// fp32 [R][C]  ->  bf16 [C][R]  (transposed weight for B-operand contiguity)
// ---------------------------------------------------------------------------
__global__ __launch_bounds__(256) void transpose_f32_bf16(
    const float* __restrict__ in, bf16* __restrict__ out, int R, int C)
{
    __shared__ float tile[32][33];
    const int cb = blockIdx.x * 32, rb = blockIdx.y * 32;
    const int c = threadIdx.x & 31, r0 = threadIdx.x >> 5;
#pragma unroll
    for (int i = 0; i < 4; ++i) {
        int r = r0 + i * 8;
        tile[r][c] = in[(size_t)(rb + r) * C + cb + c];
    }
    __syncthreads();
#pragma unroll
    for (int i = 0; i < 4; ++i) {
        int rr = r0 + i * 8;
        out[(size_t)(cb + rr) * R + rb + c] = (bf16)tile[c][rr];
    }
}

// ---------------------------------------------------------------------------
// V slice of qkv [8192][3072] -> VT [64 bh][64 d][2048 tok] bf16
// ---------------------------------------------------------------------------
__global__ __launch_bounds__(256) void transpose_v(
    const bf16* __restrict__ qkv, bf16* __restrict__ VT)
{
    __shared__ float tile[32][33];
    const int tokb = blockIdx.x * 32;
    const int db   = blockIdx.y * 32;
    const int bh   = blockIdx.z;
    const int b = bh >> 4, h = bh & 15;
    const int c = threadIdx.x & 31, r0 = threadIdx.x >> 5;
#pragma unroll
    for (int i = 0; i < 4; ++i) {
        int r = r0 + i * 8;
        tile[r][c] = (float)qkv[(size_t)(b * 2048 + tokb + r) * 3072 + 2048 + h * 64 + db + c];
    }
    __syncthreads();
#pragma unroll
    for (int i = 0; i < 4; ++i) {
        int rr = r0 + i * 8;
        VT[((size_t)bh * 64 + db + rr) * 2048 + tokb + c] = (bf16)tile[c][rr];
    }
}

// ---------------------------------------------------------------------------
// LayerNorm: one wave per token, f32 in -> bf16 out. grid 2048, block 256
// ---------------------------------------------------------------------------
__global__ __launch_bounds__(256) void ln_kernel(
    const float* __restrict__ x, const float* __restrict__ g,
    const float* __restrict__ b, bf16* __restrict__ out)
{
    const int lane = threadIdx.x & 63;
    const int wv   = threadIdx.x >> 6;
    const size_t token = (size_t)blockIdx.x * 4 + wv;
    const float* xr = x + token * 1024;
    float4 v[4];
    float s = 0.f, ss = 0.f;
#pragma unroll
    for (int c = 0; c < 4; ++c) {
        v[c] = *(const float4*)(xr + c * 256 + lane * 4);
        s  += v[c].x + v[c].y + v[c].z + v[c].w;
        ss += v[c].x * v[c].x + v[c].y * v[c].y + v[c].z * v[c].z + v[c].w * v[c].w;
    }
#pragma unroll
    for (int off = 32; off > 0; off >>= 1) {
        s  += __shfl_xor(s, off);
        ss += __shfl_xor(ss, off);
    }
    const float mu  = s * (1.0f / 1024.0f);
    const float var = ss * (1.0f / 1024.0f) - mu * mu;
    const float rs  = rsqrtf(var + 1e-5f);
    bf16* orow = out + token * 1024;
#pragma unroll
    for (int c = 0; c < 4; ++c) {
        float4 gg = *(const float4*)(g + c * 256 + lane * 4);
        float4 bb = *(const float4*)(b + c * 256 + lane * 4);
        bf16x4 o;
        o[0] = (bf16)((v[c].x - mu) * rs * gg.x + bb.x);
        o[1] = (bf16)((v[c].y - mu) * rs * gg.y + bb.y);
        o[2] = (bf16)((v[c].z - mu) * rs * gg.z + bb.z);
        o[3] = (bf16)((v[c].w - mu) * rs * gg.w + bb.w);
        *(bf16x4*)(orow + c * 256 + lane * 4) = o;
    }
}

// ---------------------------------------------------------------------------
// GEMM: A[M,K] bf16 x Bt[N,K] bf16 -> out [M,N]. 128x128 tile, BK=64,
// two-barrier K-loop. LINE-COALESCED staging: 8 consecutive lanes read the
// 8 x 16B chunks of ONE row (one 128B cache line per 8 lanes — 8x fewer L2
// line requests than row-per-lane). Chunk XOR (ch^(row&7)) folded into the
// GLOBAL address so LDS stays linear for gl_lds16; fragment ds_read_b128
// banks = 4*((s4+quad)^(l16&7)) -> conflict-free (2-way max).
// LDS tile layout: sX[row][chpos] with chpos = chunk ^ (row&7), chunk = k/8.
// Operand-swapped MFMA: lane holds 4 consecutive cols of one row.
// EPI: 0 = bf16; 1 = +bias +resid(f32) -> f32; 2 = +bias, fast GELU -> bf16
// ---------------------------------------------------------------------------
template <int EPI>
__global__ __launch_bounds__(256, 4) void gemm_bt(
    const bf16* __restrict__ A, const bf16* __restrict__ Bt,
    const float* __restrict__ bias, const float* __restrict__ resid,
    void* __restrict__ outp, int M, int N, int K)
{
    __shared__ __align__(16) bf16 sA[128 * 64];   // 16 KB
    __shared__ __align__(16) bf16 sB[128 * 64];   // 16 KB

    const int tid  = threadIdx.x;
    const int lane = tid & 63;
    const int wv   = tid >> 6;
    const int quad = lane >> 4;
    const int l16  = lane & 15;

    // XCD slab swizzle (HW heuristic: XCD = linear block id % 8)
    const int id  = blockIdx.x;
    const int xcd = id & 7, j = id >> 3;
    const int M0 = (xcd * 8 + (j & 7)) * 128;   // Mb = 64 fixed (M == 8192)
    const int N0 = (j >> 3) * 128;

    const int wm = (wv >> 1) * 64;
    const int wn = (wv & 1) * 64;

    f32x4 acc[4][4] = {};

    // staging pointers: slot f = c*256+tid -> row = f>>3, store-chunk = f&7,
    // global chunk = (f&7) ^ (row&7). 8 consecutive lanes = one 128B line.
    const bf16* paG[4];
    const bf16* pbG[4];
#pragma unroll
    for (int c = 0; c < 4; ++c) {
        const int f = c * 256 + tid;
        const int row = f >> 3;
        const int gch = (f & 7) ^ (row & 7);
        paG[c] = A  + (size_t)(M0 + row) * K + gch * 8;
        pbG[c] = Bt + (size_t)(N0 + row) * K + gch * 8;
    }

    const int sw = l16 & 7;

    for (int k0 = 0; k0 < K; k0 += 64) {
        __syncthreads();
#pragma unroll
        for (int c = 0; c < 4; ++c) {
            const int f8 = (c * 256 + tid) * 8;
            gl_lds16(paG[c] + k0, sA + f8);
            gl_lds16(pbG[c] + k0, sB + f8);
        }
        __syncthreads();

#pragma unroll
        for (int s = 0; s < 2; ++s) {
            const int chp = (s * 4 + quad) ^ sw;   // swizzled chunk position
            bf16x8 af[4], bfr[4];
#pragma unroll
            for (int t = 0; t < 4; ++t)
                af[t] = *(const bf16x8*)(sA + ((wm + t * 16 + l16) << 6) + chp * 8);
#pragma unroll
            for (int t = 0; t < 4; ++t)
                bfr[t] = *(const bf16x8*)(sB + ((wn + t * 16 + l16) << 6) + chp * 8);
#pragma unroll
            for (int tm = 0; tm < 4; ++tm)
#pragma unroll
                for (int tn = 0; tn < 4; ++tn)
                    acc[tm][tn] = MFMA_16x16x32(bfr[tn], af[tm], acc[tm][tn]);
        }
    }

    // swapped C layout: lane l16 = output row, regs r = 4 consecutive cols
#pragma unroll
    for (int tm = 0; tm < 4; ++tm) {
        const int row = M0 + wm + tm * 16 + l16;
#pragma unroll
        for (int tn = 0; tn < 4; ++tn) {
            const int col = N0 + wn + tn * 16 + quad * 4;
            const size_t idx = (size_t)row * N + col;
            const f32x4 v = acc[tm][tn];
            if (EPI == 0) {
                bf16x4 o;
#pragma unroll
                for (int r = 0; r < 4; ++r) o[r] = (bf16)v[r];
                *(bf16x4*)((bf16*)outp + idx) = o;
            } else if (EPI == 1) {
                const f32x4 b4 = *(const f32x4*)(bias + col);
                const f32x4 r4 = *(const f32x4*)(resid + idx);
                *(f32x4*)((float*)outp + idx) = v + b4 + r4;
            } else {
                const f32x4 b4 = *(const f32x4*)(bias + col);
                bf16x4 o;
#pragma unroll
                for (int r = 0; r < 4; ++r) o[r] = (bf16)fast_gelu(v[r] + b4[r]);
                *(bf16x4*)((bf16*)outp + idx) = o;
            }
        }
    }
}

// ---------------------------------------------------------------------------
// Flash attention, no-max softmax (scores ~N(0,1): exp2 args |.|<~10, safe).
// qkv: [8192][3072] bf16; VT: [64 bh][64 d][2048] bf16.
// grid (16 q-tiles, 64 bh), block 256. Wave = 32 q rows; k-tile = 64 keys.
// ---------------------------------------------------------------------------
__global__ __launch_bounds__(256, 4) void attn_kernel(
    const bf16* __restrict__ qkv, const bf16* __restrict__ VT,
    bf16* __restrict__ attn_out)
{
    __shared__ __align__(16) bf16 sK[4096];
    __shared__ __align__(16) bf16 sV[4096];
    __shared__ __align__(16) bf16 sP[4][32][72];

    const int bh = blockIdx.y, b = bh >> 4, h = bh & 15;
    const int tid = threadIdx.x, lane = tid & 63, wv = tid >> 6;
    const int quad = lane >> 4, l16 = lane & 15;
    const size_t tok0 = (size_t)b * 2048;
    const int q0 = blockIdx.x * 128 + wv * 32;

    bf16x8 qf[2][2];
#pragma unroll
    for (int mi = 0; mi < 2; ++mi)
#pragma unroll
        for (int c = 0; c < 2; ++c) {
            bf16x8 t = *(const bf16x8*)(qkv + (tok0 + q0 + mi * 16 + l16) * 3072 + h * 64 + c * 32 + quad * 8);
#pragma unroll
            for (int j = 0; j < 8; ++j) t[j] = (bf16)((float)t[j] * 0.18033688011112042f);
            qf[mi][c] = t;
        }

    f32x4 o[2][4] = {};
    float l[2][4] = {};

    const int fA = tid, fB = tid + 256;
    const int cKA = fA >> 8, keyA = (fA >> 2) & 63, qcA = fA & 3;
    const int cKB = fB >> 8, keyB = (fB >> 2) & 63, qcB = fB & 3;
    const int dVA = fA >> 3, ccA = fA & 7;
    const int dVB = fB >> 3, ccB = fB & 7;
    const bf16* Kb = qkv + 1024 + h * 64;
    const bf16* Vb = VT + (size_t)bh * 64 * 2048;

    for (int kt = 0; kt < 32; ++kt) {
        const int kb = kt * 64;
        __syncthreads();
        gl_lds16(Kb + (tok0 + kb + keyA) * 3072 + cKA * 32 + ((qcA ^ (keyA & 3)) * 8), sK + fA * 8);
        gl_lds16(Kb + (tok0 + kb + keyB) * 3072 + cKB * 32 + ((qcB ^ (keyB & 3)) * 8), sK + fB * 8);
        gl_lds16(Vb + (size_t)dVA * 2048 + kb + ((ccA ^ (dVA & 7)) * 8), sV + fA * 8);
        gl_lds16(Vb + (size_t)dVB * 2048 + kb + ((ccB ^ (dVB & 7)) * 8), sV + fB * 8);
        __syncthreads();

        f32x4 s[2][4];
#pragma unroll
        for (int ct = 0; ct < 4; ++ct) {
            const int key = ct * 16 + l16;
            const int ch = quad ^ (l16 & 3);
            bf16x8 k0 = *(const bf16x8*)(sK + (key * 4 + ch) * 8);
            bf16x8 k1 = *(const bf16x8*)(sK + (256 + key * 4 + ch) * 8);
#pragma unroll
            for (int mi = 0; mi < 2; ++mi) {
                f32x4 z = {};
                z = MFMA_16x16x32(qf[mi][0], k0, z);
                z = MFMA_16x16x32(qf[mi][1], k1, z);
                s[mi][ct] = z;
            }
        }
#pragma unroll
        for (int mi = 0; mi < 2; ++mi)
#pragma unroll
            for (int ct = 0; ct < 4; ++ct)
#pragma unroll
                for (int r = 0; r < 4; ++r) {
                    const float p = __builtin_amdgcn_exp2f(s[mi][ct][r]);
                    l[mi][r] += p;
                    sP[wv][mi * 16 + quad * 4 + r][ct * 16 + l16] = (bf16)p;
                }
        bf16x8 vb[4][2];
#pragma unroll
        for (int dt = 0; dt < 4; ++dt) {
            const int d = dt * 16 + l16;
            vb[dt][0] = *(const bf16x8*)(sV + (d * 8 + (quad ^ (l16 & 7))) * 8);
            vb[dt][1] = *(const bf16x8*)(sV + (d * 8 + ((quad + 4) ^ (l16 & 7))) * 8);
        }
#pragma unroll
        for (int mi = 0; mi < 2; ++mi) {
            bf16x8 p0 = *(const bf16x8*)&sP[wv][mi * 16 + l16][quad * 8];
            bf16x8 p1 = *(const bf16x8*)&sP[wv][mi * 16 + l16][32 + quad * 8];
#pragma unroll
            for (int dt = 0; dt < 4; ++dt) {
                o[mi][dt] = MFMA_16x16x32(p0, vb[dt][0], o[mi][dt]);
                o[mi][dt] = MFMA_16x16x32(p1, vb[dt][1], o[mi][dt]);
            }
        }
    }

#pragma unroll
    for (int mi = 0; mi < 2; ++mi) {
        float rl[4];
#pragma unroll
        for (int r = 0; r < 4; ++r) {
            float t = l[mi][r];
            t += __shfl_xor(t, 1); t += __shfl_xor(t, 2);
            t += __shfl_xor(t, 4); t += __shfl_xor(t, 8);
            rl[r] = 1.0f / t;
        }
#pragma unroll
        for (int dt = 0; dt < 4; ++dt)
#pragma unroll
            for (int r = 0; r < 4; ++r) {
                const size_t tok = tok0 + q0 + mi * 16 + quad * 4 + r;
                attn_out[tok * 1024 + h * 64 + dt * 16 + l16] = (bf16)(o[mi][dt][r] * rl[r]);
            }
    }
}

// ---------------------------------------------------------------------------
extern "C" void kernel_launch(void* const* d_in, const int* in_sizes, int n_in,
                              void* d_out, int out_size, void* d_ws, size_t ws_size,
                              hipStream_t stream)
{
    const float* x     = (const float*)d_in[0];
    const float* ln1_g = (const float*)d_in[1];
    const float* ln1_b = (const float*)d_in[2];
    const float* w_qkv = (const float*)d_in[3];
    const float* w_out = (const float*)d_in[4];
    const float* b_out = (const float*)d_in[5];
    const float* ln2_g = (const float*)d_in[6];
    const float* ln2_b = (const float*)d_in[7];
    const float* w1    = (const float*)d_in[8];
    const float* b1    = (const float*)d_in[9];
    const float* w2    = (const float*)d_in[10];
    const float* b2    = (const float*)d_in[11];
    float* out = (float*)d_out;

    char* ws = (char*)d_ws;
    bf16*  h      = (bf16*)(ws);                    // 16 MB
    bf16*  big    = (bf16*)(ws + 16777216);         // 64 MB (qkv, then mlp1)
    bf16*  attn_o = (bf16*)(ws + 83886080);         // 16 MB
    float* x_mid  = (float*)(ws + 100663296);       // 32 MB
    bf16*  VT     = (bf16*)(ws + 100663296);        // 16 MB (dead before x_mid)
    bf16*  wT_qkv = (bf16*)(ws + 134217728);
    bf16*  wT_out = (bf16*)(ws + 140509184);
    bf16*  wT_1   = (bf16*)(ws + 142606336);
    bf16*  wT_2   = (bf16*)(ws + 150994944);

    transpose_f32_bf16<<<dim3(3072/32, 1024/32), 256, 0, stream>>>(w_qkv, wT_qkv, 1024, 3072);
    transpose_f32_bf16<<<dim3(1024/32, 1024/32), 256, 0, stream>>>(w_out, wT_out, 1024, 1024);
    transpose_f32_bf16<<<dim3(4096/32, 1024/32), 256, 0, stream>>>(w1,    wT_1,   1024, 4096);
    transpose_f32_bf16<<<dim3(1024/32, 4096/32), 256, 0, stream>>>(w2,    wT_2,   4096, 1024);

    ln_kernel<<<2048, 256, 0, stream>>>(x, ln1_g, ln1_b, h);

    // 1D grids: Mb=64 always; block count = 64 * (N/128)
    gemm_bt<0><<<64 * 24, 256, 0, stream>>>(h, wT_qkv, nullptr, nullptr, big, 8192, 3072, 1024);

    transpose_v<<<dim3(64, 2, 64), 256, 0, stream>>>(big, VT);

    attn_kernel<<<dim3(16, 64), 256, 0, stream>>>(big, VT, attn_o);

    gemm_bt<1><<<64 * 8, 256, 0, stream>>>(attn_o, wT_out, b_out, x, x_mid, 8192, 1024, 1024);

    ln_kernel<<<2048, 256, 0, stream>>>(x_mid, ln2_g, ln2_b, h);

    gemm_bt<2><<<64 * 32, 256, 0, stream>>>(h, wT_1, b1, nullptr, big, 8192, 4096, 1024);

    gemm_bt<1><<<64 * 8, 256, 0, stream>>>(big, wT_2, b2, x_mid, out, 8192, 1024, 4096);
}